// Round 5
// baseline (731.837 us; speedup 1.0000x reference)
//
#include <hip/hip_runtime.h>
#include <hip/hip_fp16.h>

// Output layout (flat): forces[n_atoms*3] | virial[n_images*9] | stress[n_images*9]
//
// v5: k_scatter proved scattered-WRITE-path bound (WRITE_SIZE 459 MB = 2.2x
// amplification of 205 MB of random 16 B stores, ~1.9 TB/s random-write
// ceiling). Halve the payload: entry = 8 B {half dx,dy,dz; local atom id}.
// Output tolerance is 14.3 abs (we sit at 2.0); fp16 edge payload adds <0.05.
// Virial stays f32. ws need drops 205 -> ~103 MB.

typedef unsigned int uint;
typedef unsigned short ushort;

#define SLICES  256         // count/scatter blocks (1024 threads each)
#define BASHIFT 8           // 256 atoms per bucket
#define NBCAP   1024        // max buckets (n_atoms <= 256k)
#define NVMAX   1152        // n_images*9 cap (128 images)

__device__ __forceinline__ uint2 pack_entry(float dx, float dy, float dz, uint local) {
    const __half2 hxy = __floats2half2_rn(dx, dy);
    const ushort  hz  = __half_as_ushort(__float2half_rn(dz));
    uint2 r;
    r.x = *(const uint*)&hxy;
    r.y = (uint)hz | (local << 16);
    return r;
}

// ---------------- K1: per-(slice,bucket) histogram ----------------
__global__ __launch_bounds__(1024) void k_count(
    const int2* __restrict__ edge_idx, uint* __restrict__ counts,
    int n_edges, int es, int nb)
{
    __shared__ uint hist[NBCAP];
    for (int t = threadIdx.x; t < nb; t += blockDim.x) hist[t] = 0;
    __syncthreads();
    const int s  = blockIdx.x;
    const int e0 = s * es;
    const int e1 = min(n_edges, e0 + es);
    for (int e = e0 + threadIdx.x; e < e1; e += blockDim.x) {
        const int2 ij = edge_idx[e];
        atomicAdd(&hist[((uint)ij.x) >> BASHIFT], 1u);
        atomicAdd(&hist[((uint)ij.y) >> BASHIFT], 1u);
    }
    __syncthreads();
    for (int b = threadIdx.x; b < nb; b += blockDim.x)
        counts[(size_t)b * SLICES + s] = hist[b];   // bucket-major
}

// ---------------- K2a: row sums (one block per bucket) ----------------
__global__ __launch_bounds__(SLICES) void k_rowsum(
    const uint* __restrict__ counts, uint* __restrict__ rowsum)
{
    __shared__ uint red[SLICES];
    const int b = blockIdx.x;
    red[threadIdx.x] = counts[(size_t)b * SLICES + threadIdx.x];
    __syncthreads();
    for (int off = SLICES / 2; off > 0; off >>= 1) {
        if (threadIdx.x < off) red[threadIdx.x] += red[threadIdx.x + off];
        __syncthreads();
    }
    if (threadIdx.x == 0) rowsum[b] = red[0];
}

// ---------------- K2b: exclusive scan of row sums (single block) --------
__global__ __launch_bounds__(1024) void k_scan_rows(
    const uint* __restrict__ rowsum, uint* __restrict__ rowoff, int nb)
{
    __shared__ uint psum[1024];
    const int t = threadIdx.x;
    psum[t] = (t < nb) ? rowsum[t] : 0u;
    __syncthreads();
    for (int off = 1; off < 1024; off <<= 1) {
        uint v = (t >= off) ? psum[t - off] : 0u;
        __syncthreads();
        psum[t] += v;
        __syncthreads();
    }
    if (t < nb) rowoff[t] = (t == 0) ? 0u : psum[t - 1];
}

// ---------------- K2c: per-row exclusive scan + global offset ----------
__global__ __launch_bounds__(SLICES) void k_rowscan(
    uint* __restrict__ counts, const uint* __restrict__ rowoff)
{
    __shared__ uint psum[SLICES];
    const int b = blockIdx.x;
    const int t = threadIdx.x;
    const uint c = counts[(size_t)b * SLICES + t];
    psum[t] = c;
    __syncthreads();
    for (int off = 1; off < SLICES; off <<= 1) {
        uint v = (t >= off) ? psum[t - off] : 0u;
        __syncthreads();
        psum[t] += v;
        __syncthreads();
    }
    counts[(size_t)b * SLICES + t] = rowoff[b] + psum[t] - c;  // exclusive
}

// ---------------- K3: scatter 8 B entries + virial ----------------
__global__ __launch_bounds__(1024) void k_scatter(
    const float* __restrict__ edge_diff, const float* __restrict__ dE_ddiff,
    const int2* __restrict__ edge_idx, const int* __restrict__ image_idx,
    const uint* __restrict__ offsets, uint2* __restrict__ entries,
    float* __restrict__ virial /* zeroed */, int n_edges, int es, int nb, int nv)
{
    __shared__ uint  cur[NBCAP];
    __shared__ float lv[NVMAX];
    const int s = blockIdx.x;
    for (int t = threadIdx.x; t < nb; t += blockDim.x)
        cur[t] = offsets[(size_t)t * SLICES + s];
    for (int t = threadIdx.x; t < nv; t += blockDim.x) lv[t] = 0.f;
    __syncthreads();

    const int e0 = s * es;
    const int e1 = min(n_edges, e0 + es);
    for (int e = e0 + threadIdx.x; e < e1; e += blockDim.x) {
        const int2 ij = edge_idx[e];
        const float dx = dE_ddiff[3*e + 0];
        const float dy = dE_ddiff[3*e + 1];
        const float dz = dE_ddiff[3*e + 2];

        const uint ai = (uint)ij.x, aj = (uint)ij.y;
        const uint pi = atomicAdd(&cur[ai >> BASHIFT], 1u);
        entries[pi] = pack_entry(dx, dy, dz, ai & ((1u << BASHIFT) - 1u));
        const uint pj = atomicAdd(&cur[aj >> BASHIFT], 1u);
        entries[pj] = pack_entry(-dx, -dy, -dz, aj & ((1u << BASHIFT) - 1u));

        const float ex = edge_diff[3*e + 0];
        const float ey = edge_diff[3*e + 1];
        const float ez = edge_diff[3*e + 2];
        float* v = &lv[image_idx[ai] * 9];
        atomicAdd(&v[0], ex*dx); atomicAdd(&v[1], ex*dy); atomicAdd(&v[2], ex*dz);
        atomicAdd(&v[3], ey*dx); atomicAdd(&v[4], ey*dy); atomicAdd(&v[5], ey*dz);
        atomicAdd(&v[6], ez*dx); atomicAdd(&v[7], ez*dy); atomicAdd(&v[8], ez*dz);
    }
    __syncthreads();
    for (int t = threadIdx.x; t < nv; t += blockDim.x) {
        const float val = lv[t];
        if (val != 0.f) unsafeAtomicAdd(&virial[t], val);
    }
}

// ---------------- K4: gather per bucket -> forces (no global atomics) ----
__global__ __launch_bounds__(256) void k_gather(
    const uint2* __restrict__ entries, const uint* __restrict__ offsets,
    float* __restrict__ forces, int n_atoms, int nb, uint total)
{
    __shared__ float tile[3 << BASHIFT];     // 256*3 floats = 3 KB
    const int q = blockIdx.x;
    for (int t = threadIdx.x; t < (3 << BASHIFT); t += blockDim.x) tile[t] = 0.f;
    __syncthreads();

    const uint beg = offsets[(size_t)q * SLICES];
    const uint end = (q + 1 < nb) ? offsets[(size_t)(q + 1) * SLICES] : total;
    for (uint k = beg + threadIdx.x; k < end; k += blockDim.x) {
        const uint2 ent = entries[k];
        const float2 xy = __half22float2(*(const __half2*)&ent.x);
        const float  z  = __half2float(__ushort_as_half((ushort)(ent.y & 0xffffu)));
        const uint local = ent.y >> 16;
        atomicAdd(&tile[local*3 + 0], xy.x);
        atomicAdd(&tile[local*3 + 1], xy.y);
        atomicAdd(&tile[local*3 + 2], z);
    }
    __syncthreads();

    const int base = q << BASHIFT;
    const int lim3 = min(n_atoms - base, 1 << BASHIFT) * 3;
    for (int t = threadIdx.x; t < lim3; t += blockDim.x)
        forces[(size_t)base * 3 + t] = tile[t];
}

// ---------------- K5: stress ----------------
__global__ void k_stress(const float* __restrict__ cell,
                         const float* __restrict__ virial,
                         float* __restrict__ stress, int n_images)
{
    const int t = blockIdx.x * blockDim.x + threadIdx.x;
    if (t >= n_images * 9) return;
    const float* c = &cell[(t / 9) * 9];
    const float crx = c[4]*c[8] - c[5]*c[7];
    const float cry = c[5]*c[6] - c[3]*c[8];
    const float crz = c[3]*c[7] - c[4]*c[6];
    const float vol = c[0]*crx + c[1]*cry + c[2]*crz;
    stress[t] = virial[t] * (-1.0f / vol);
}

// ---------------- fallback (round-1) path ----------------
__global__ __launch_bounds__(256) void edge_kernel_fb(
    const float* __restrict__ edge_diff, const float* __restrict__ dE_ddiff,
    const int2* __restrict__ edge_idx, const int* __restrict__ image_idx,
    float* __restrict__ forces, float* __restrict__ virial,
    int n_edges, int n_images)
{
    extern __shared__ float lds_v[];
    const int nv = n_images * 9;
    for (int t = threadIdx.x; t < nv; t += blockDim.x) lds_v[t] = 0.f;
    __syncthreads();
    const int stride = gridDim.x * blockDim.x;
    for (int e = blockIdx.x * blockDim.x + threadIdx.x; e < n_edges; e += stride) {
        const int2 ij = edge_idx[e];
        const int i = ij.x, j = ij.y;
        const float dx = dE_ddiff[3*e+0], dy = dE_ddiff[3*e+1], dz = dE_ddiff[3*e+2];
        unsafeAtomicAdd(&forces[3*i+0],  dx);
        unsafeAtomicAdd(&forces[3*i+1],  dy);
        unsafeAtomicAdd(&forces[3*i+2],  dz);
        unsafeAtomicAdd(&forces[3*j+0], -dx);
        unsafeAtomicAdd(&forces[3*j+1], -dy);
        unsafeAtomicAdd(&forces[3*j+2], -dz);
        const float ex = edge_diff[3*e+0], ey = edge_diff[3*e+1], ez = edge_diff[3*e+2];
        float* v = &lds_v[image_idx[i] * 9];
        atomicAdd(&v[0], ex*dx); atomicAdd(&v[1], ex*dy); atomicAdd(&v[2], ex*dz);
        atomicAdd(&v[3], ey*dx); atomicAdd(&v[4], ey*dy); atomicAdd(&v[5], ey*dz);
        atomicAdd(&v[6], ez*dx); atomicAdd(&v[7], ez*dy); atomicAdd(&v[8], ez*dz);
    }
    __syncthreads();
    for (int t = threadIdx.x; t < nv; t += blockDim.x) {
        const float val = lds_v[t];
        if (val != 0.f) unsafeAtomicAdd(&virial[t], val);
    }
}

extern "C" void kernel_launch(void* const* d_in, const int* in_sizes, int n_in,
                              void* d_out, int out_size, void* d_ws, size_t ws_size,
                              hipStream_t stream)
{
    const float* edge_diff = (const float*)d_in[0];
    const float* dE_ddiff  = (const float*)d_in[1];
    const float* cell      = (const float*)d_in[2];
    const int2*  edge_idx  = (const int2*)d_in[3];
    const int*   image_idx = (const int*)d_in[4];

    const int n_edges  = in_sizes[0] / 3;
    const int n_images = in_sizes[2] / 9;
    const int n_atoms  = in_sizes[4];
    const int nv       = n_images * 9;

    float* out    = (float*)d_out;
    float* forces = out;
    float* virial = out + (size_t)n_atoms * 3;
    float* stress = virial + nv;

    const int nb = (n_atoms + (1 << BASHIFT) - 1) >> BASHIFT;
    const int es = (n_edges + SLICES - 1) / SLICES;
    const uint total = (uint)(2 * (size_t)n_edges);

    const size_t entries_bytes = (size_t)total * sizeof(uint2);
    const size_t counts_bytes  = (size_t)nb * SLICES * sizeof(uint);
    const size_t aux_bytes     = 2 * (size_t)NBCAP * sizeof(uint);
    const size_t need = entries_bytes + counts_bytes + aux_bytes;

    if (ws_size >= need && nb <= NBCAP && nv <= NVMAX) {
        uint2* entries = (uint2*)d_ws;
        uint*  offsets = (uint*)((char*)d_ws + entries_bytes);
        uint*  rowsum  = offsets + (size_t)nb * SLICES;
        uint*  rowoff  = rowsum + NBCAP;

        hipMemsetAsync(virial, 0, nv * sizeof(float), stream);

        k_count<<<SLICES, 1024, 0, stream>>>(edge_idx, offsets, n_edges, es, nb);
        k_rowsum<<<nb, SLICES, 0, stream>>>(offsets, rowsum);
        k_scan_rows<<<1, 1024, 0, stream>>>(rowsum, rowoff, nb);
        k_rowscan<<<nb, SLICES, 0, stream>>>(offsets, rowoff);
        k_scatter<<<SLICES, 1024, 0, stream>>>(edge_diff, dE_ddiff, edge_idx, image_idx,
                                               offsets, entries, virial, n_edges, es, nb, nv);
        k_gather<<<nb, 256, 0, stream>>>(entries, offsets, forces, n_atoms, nb, total);
        k_stress<<<(nv + 255) / 256, 256, 0, stream>>>(cell, virial, stress, n_images);
    } else {
        hipMemsetAsync(out, 0, ((size_t)n_atoms * 3 + nv) * sizeof(float), stream);
        edge_kernel_fb<<<2048, 256, nv * sizeof(float), stream>>>(
            edge_diff, dE_ddiff, edge_idx, image_idx, forces, virial, n_edges, n_images);
        k_stress<<<(nv + 255) / 256, 256, 0, stream>>>(cell, virial, stress, n_images);
    }
}